// Round 1
// 348.254 us; speedup vs baseline: 1.0131x; 1.0131x over previous
//
#include <hip/hip_runtime.h>
#include <math.h>

#define B_   4
#define N_   4096
#define D_   1024
#define DFF_ 4096
#define K_   2048

typedef __attribute__((ext_vector_type(8))) short short8;
typedef __attribute__((ext_vector_type(4))) float float4v;

__device__ __forceinline__ unsigned short f2bf(float f) {
    unsigned int u = __float_as_uint(f);
    u = (u + 0x7fffu + ((u >> 16) & 1u)) >> 16;   // RNE
    return (unsigned short)u;
}

__device__ __forceinline__ void gld16(const void* g, void* l) {
    __builtin_amdgcn_global_load_lds((const __attribute__((address_space(1))) void*)g,
                                     (__attribute__((address_space(3))) void*)l, 16, 0, 0);
}

// ---------------- scores (bit-identical selection math) + slot clear ----------------
__global__ __launch_bounds__(256) void scores_kernel(const float* __restrict__ x,
                                                     const float* __restrict__ gate_w,
                                                     float* __restrict__ scores,
                                                     int* __restrict__ slot) {
    int wave = (blockIdx.x * blockDim.x + threadIdx.x) >> 6;
    int lane = threadIdx.x & 63;
    if (wave >= B_ * N_) return;
    if (lane == 1) slot[wave] = -1;
    const float4* xr = (const float4*)(x + (size_t)wave * D_);
    const float4* g  = (const float4*)gate_w;
    float acc = 0.f;
    #pragma unroll
    for (int j = 0; j < D_ / 4 / 64; ++j) {
        float4 a = xr[lane + j * 64];
        float4 b = g[lane + j * 64];
        acc += a.x * b.x + a.y * b.y + a.z * b.z + a.w * b.w;
    }
    #pragma unroll
    for (int off = 32; off > 0; off >>= 1) acc += __shfl_down(acc, off, 64);
    if (lane == 0) scores[wave] = acc;
}

// ---------------- top-k radix select, wave-level scans; writes topk + global slot map ----------------
__global__ __launch_bounds__(1024) void select_topk_kernel(const float* __restrict__ scores,
                                                           int* __restrict__ topk,
                                                           int* __restrict__ slot) {
    __shared__ unsigned key[N_];
    __shared__ unsigned hist[256];
    __shared__ int sh_bin, sh_rem, sh_ngt;
    __shared__ int wsum[16], woff[16];
    int b = blockIdx.x, tid = threadIdx.x;
    int lane = tid & 63, wid = tid >> 6;

    for (int i = tid; i < N_; i += 1024) {
        unsigned u = __float_as_uint(scores[b * N_ + i]);
        key[i] = (u & 0x80000000u) ? ~u : (u | 0x80000000u);   // monotonic map
    }
    if (tid == 0) sh_ngt = 0;
    __syncthreads();

    unsigned prefix = 0, pmask = 0;
    int rem = K_;
    for (int shift = 24; shift >= 0; shift -= 8) {
        if (tid < 256) hist[tid] = 0;
        __syncthreads();
        for (int i = tid; i < N_; i += 1024) {
            unsigned k = key[i];
            if ((k & pmask) == prefix) atomicAdd(&hist[(k >> shift) & 255u], 1u);
        }
        __syncthreads();
        if (tid < 64) {   // wave 0: suffix scan of 256 bins, 4 bins/lane
            unsigned v0 = hist[4 * lane], v1 = hist[4 * lane + 1];
            unsigned v2 = hist[4 * lane + 2], v3 = hist[4 * lane + 3];
            unsigned s3 = v3, s2 = v2 + s3, s1 = v1 + s2, s0 = v0 + s1;
            unsigned t = s0;
            #pragma unroll
            for (int off = 1; off < 64; off <<= 1) {
                unsigned u = __shfl_down(t, off, 64);
                if (lane + off < 64) t += u;
            }
            unsigned above = t - s0;                  // keys in bins > 4*lane+3
            unsigned S0 = s0 + above, S1 = s1 + above, S2 = s2 + above, S3 = s3 + above;
            unsigned R = (unsigned)rem;
            if (S0 >= R && S1 < R) { sh_bin = 4 * lane;     sh_rem = rem - (int)S1; }
            if (S1 >= R && S2 < R) { sh_bin = 4 * lane + 1; sh_rem = rem - (int)S2; }
            if (S2 >= R && S3 < R) { sh_bin = 4 * lane + 2; sh_rem = rem - (int)S3; }
            if (S3 >= R && above < R) { sh_bin = 4 * lane + 3; sh_rem = rem - (int)above; }
        }
        __syncthreads();
        prefix |= ((unsigned)sh_bin) << shift;
        pmask  |= 0xffu << shift;
        rem = sh_rem;
    }
    unsigned T = prefix;          // exact key of k-th largest
    int c_gt = K_ - rem;          // count strictly greater

    // strictly-greater: ballot-compacted, arbitrary order, slots [0, c_gt)
    for (int i = tid; i < N_; i += 1024) {
        bool p = key[i] > T;
        unsigned long long m = __ballot(p);
        int cnt = __popcll(m);
        int basepos = 0;
        if (lane == 0 && cnt) basepos = atomicAdd(&sh_ngt, cnt);
        basepos = __shfl(basepos, 0, 64);
        if (p) {
            int pos = basepos + __popcll(m & ((1ULL << lane) - 1ULL));
            topk[b * K_ + pos] = i;
            slot[b * N_ + i] = b * K_ + pos;
        }
    }
    // ties: first `rem` by index -> slots [c_gt, K)
    int base = tid * 4, c = 0;
    #pragma unroll
    for (int j = 0; j < 4; ++j) c += (key[base + j] == T);
    int sc = c;
    #pragma unroll
    for (int off = 1; off < 64; off <<= 1) {
        int u = __shfl_up(sc, off, 64);
        if (lane >= off) sc += u;
    }
    if (lane == 63) wsum[wid] = sc;
    __syncthreads();
    if (tid == 0) {
        int run = 0;
        #pragma unroll
        for (int j = 0; j < 16; ++j) { woff[j] = run; run += wsum[j]; }
    }
    __syncthreads();
    int r = woff[wid] + sc - c;   // exclusive prefix among ties
    #pragma unroll
    for (int j = 0; j < 4; ++j) {
        if (key[base + j] == T) {
            if (r < rem) {
                topk[b * K_ + c_gt + r] = base + j;
                slot[b * N_ + base + j] = b * K_ + c_gt + r;
            }
            ++r;
        }
    }
}

// ---------------- fused: selected rows -> bf16 xsel[slot]; unselected -> out copy ----------------
__global__ __launch_bounds__(256) void gather_copy_kernel(const float* __restrict__ x,
                                                          const int* __restrict__ slot,
                                                          unsigned short* __restrict__ xsel,
                                                          float* __restrict__ out) {
    int row = blockIdx.x;
    int t = threadIdx.x;
    int s = slot[row];
    float4 v = ((const float4*)(x + (size_t)row * D_))[t];
    if (s >= 0) {
        ushort4 o;
        o.x = f2bf(v.x); o.y = f2bf(v.y); o.z = f2bf(v.z); o.w = f2bf(v.w);
        ((ushort4*)(xsel + (size_t)s * D_))[t] = o;
    } else {
        ((float4*)(out + (size_t)row * D_))[t] = v;
    }
}

// ---------------- both weight transposes (fp32 [R][C] -> bf16 [C][R]) in one launch ----------------
__global__ __launch_bounds__(256) void transpose_both_kernel(const float* __restrict__ w1,
                                                             const float* __restrict__ w2,
                                                             unsigned short* __restrict__ w1t,
                                                             unsigned short* __restrict__ w2t) {
    __shared__ float tile[32][33];
    int bid = blockIdx.x;
    const float* src; unsigned short* dst; int R, C, bx, by;
    if (bid < 4096) { src = w1; dst = w1t; R = D_;   C = DFF_; bx = bid & 127;          by = bid >> 7; }
    else            { src = w2; dst = w2t; R = DFF_; C = D_;   bx = (bid - 4096) & 31;  by = (bid - 4096) >> 5; }
    int tx = threadIdx.x & 31, ty = threadIdx.x >> 5;   // 32 x 8
    int c = bx * 32 + tx, r0 = by * 32;
    #pragma unroll
    for (int j = ty; j < 32; j += 8) tile[j][tx] = src[(size_t)(r0 + j) * C + c];
    __syncthreads();
    int dc = by * 32 + tx, dr0 = bx * 32;
    #pragma unroll
    for (int j = ty; j < 32; j += 8) dst[(size_t)(dr0 + j) * R + dc] = f2bf(tile[tx][j]);
}

// ---------------- MFMA GEMM 1 (pipelined): h1 = gelu(x_sel @ w1 + b1) ----------------
// 256x256 tile, BK=32, 512 threads (8 waves, 2Mx4N), ring of 4 K-tile LDS buffers,
// staged 3 tiles ahead via global_load_lds; counted vmcnt(8) once per K-tile;
// chunk-XOR swizzle (applied to global src + ds_read addr; LDS dest linear).
__global__ __launch_bounds__(512, 2) void ffn1_pipe_kernel(const unsigned short* __restrict__ A,
                                                           const unsigned short* __restrict__ Bt,
                                                           const float* __restrict__ b1,
                                                           unsigned short* __restrict__ h1) {
    constexpr int K  = D_;        // 1024
    constexpr int NT = K / 32;    // 32 K-tiles
    __shared__ __align__(16) unsigned short smem[65536];   // 4 x (A 8192 + B 8192 shorts) = 128 KiB

    const int t    = threadIdx.x;
    const int lane = t & 63;
    const int wid  = t >> 6;
    const int quad = lane >> 4;
    const int lr   = lane & 15;
    const int wr   = wid >> 2;            // 0..1  (M)
    const int wc   = wid & 3;             // 0..3  (N)
    const int row0 = blockIdx.x * 256;
    const int col0 = blockIdx.y * 256;

    // staging: thread t owns chunks t and t+512 of each 16 KiB (1024-chunk) region.
    // LDS dest is LINEAR (chunk ch at byte ch*16); global src chunk is pre-swizzled:
    // LDS slot s of row r holds global k-chunk (s ^ (r&3)).
    const int ch0 = t, ch1 = t + 512;
    const int r0 = ch0 >> 2, c0 = (ch0 & 3) ^ (r0 & 3);
    const int r1 = ch1 >> 2, c1 = (ch1 & 3) ^ (r1 & 3);
    const char* aS0 = (const char*)A  + ((size_t)(row0 + r0) * K + (size_t)c0 * 8) * 2;
    const char* aS1 = (const char*)A  + ((size_t)(row0 + r1) * K + (size_t)c1 * 8) * 2;
    const char* bS0 = (const char*)Bt + ((size_t)(col0 + r0) * K + (size_t)c0 * 8) * 2;
    const char* bS1 = (const char*)Bt + ((size_t)(col0 + r1) * K + (size_t)c1 * 8) * 2;
    const int oA0 = ch0 * 8, oA1 = ch1 * 8;             // short offsets in buffer
    const int oB0 = 8192 + ch0 * 8, oB1 = 8192 + ch1 * 8;

    // fragment reads: true chunk `quad` of row lives at slot quad ^ (row&3); row&3 == lr&3.
    const int sw   = ((quad ^ (lr & 3)) * 8);
    const int aoff = (wr * 128 + lr) * 32 + sw;
    const int boff = 8192 + (wc * 64 + lr) * 32 + sw;

    // ---- prologue: stage K-tiles 0,1,2 into ring bufs 0,1,2 ----
    #pragma unroll
    for (int pt = 0; pt < 3; ++pt) {
        unsigned short* buf = smem + pt * 16384;
        gld16(aS0, buf + oA0); gld16(aS1, buf + oA1);
        gld16(bS0, buf + oB0); gld16(bS1, buf + oB1);
        aS0 += 64; aS1 += 64; bS0 += 64; bS1 += 64;
    }
    asm volatile("s_waitcnt vmcnt(8)" ::: "memory");   // tile 0 landed; tiles 1,2 in flight
    __builtin_amdgcn_s_barrier();

    float4v acc[8][4] = {};
    short8 af[8], bq[4];

    #pragma unroll 4
    for (int kt = 0; kt < NT; ++kt) {
        unsigned short* cur = smem + (kt & 3) * 16384;
        unsigned short* nxt = smem + ((kt + 3) & 3) * 16384;
        const bool pf = (kt + 3 < NT);

        // ---------- phase A: frags mi 0-3 + all B frags; stage A-half of tile kt+3 ----------
        #pragma unroll
        for (int mi = 0; mi < 4; ++mi) af[mi] = *(const short8*)(cur + aoff + mi * 512);
        #pragma unroll
        for (int ni = 0; ni < 4; ++ni) bq[ni] = *(const short8*)(cur + boff + ni * 512);
        if (pf) { gld16(aS0, nxt + oA0); gld16(aS1, nxt + oA1); }
        __builtin_amdgcn_s_barrier();
        __builtin_amdgcn_s_setprio(1);
        #pragma unroll
        for (int mi = 0; mi < 4; ++mi)
            #pragma unroll
            for (int ni = 0; ni < 4; ++ni)
                acc[mi][ni] = __builtin_amdgcn_mfma_f32_16x16x32_bf16(af[mi], bq[ni], acc[mi][ni], 0, 0, 0);
        __builtin_amdgcn_s_setprio(0);
        __builtin_amdgcn_s_barrier();

        // ---------- phase B: frags mi 4-7 (B reused); stage B-half of tile kt+3 ----------
        #pragma unroll
        for (int mi = 4; mi < 8; ++mi) af[mi] = *(const short8*)(cur + aoff + mi * 512);
        if (pf) { gld16(bS0, nxt + oB0); gld16(bS1, nxt + oB1); }
        aS0 += 64; aS1 += 64; bS0 += 64; bS1 += 64;
        // counted vmcnt: allow tiles kt+2,kt+3 (8 loads) in flight; guarantees kt+1 landed.
        if (kt < NT - 3)       asm volatile("s_waitcnt vmcnt(8)" ::: "memory");
        else if (kt == NT - 3) asm volatile("s_waitcnt vmcnt(4)" ::: "memory");
        else                   asm volatile("s_waitcnt vmcnt(0)" ::: "memory");
        __builtin_amdgcn_s_barrier();
        __builtin_amdgcn_s_setprio(1);
        #pragma unroll
        for (int mi = 4; mi < 8; ++mi)
            #pragma unroll
            for (int ni = 0; ni < 4; ++ni)
                acc[mi][ni] = __builtin_amdgcn_mfma_f32_16x16x32_bf16(af[mi], bq[ni], acc[mi][ni], 0, 0, 0);
        __builtin_amdgcn_s_setprio(0);
        __builtin_amdgcn_s_barrier();
    }

    // ---- epilogue: bias+GELU -> bf16 via per-wave-private LDS (128 rows x 40 shorts), 2 col-half passes ----
    float bias[4];
    #pragma unroll
    for (int ni = 0; ni < 4; ++ni) bias[ni] = b1[col0 + wc * 64 + ni * 16 + lr];
    unsigned short* ws_ = smem + wid * 5120;
    const int ro = row0 + wr * 128;
    const int co = col0 + wc * 64;
    #pragma unroll
    for (int p = 0; p < 2; ++p) {
        #pragma unroll
        for (int mi = 0; mi < 8; ++mi)
            #pragma unroll
            for (int nj = 0; nj < 2; ++nj) {
                const int ni = p * 2 + nj;
                #pragma unroll
                for (int r = 0; r < 4; ++r) {
                    float u = acc[mi][ni][r] + bias[ni];
                    float tt = 1.5957691216057308f * u * (1.0f + 0.044715f * u * u);
                    float g = u / (1.0f + __expf(-tt));
                    ws_[(mi * 16 + quad * 4 + r) * 40 + nj * 16 + lr] = f2bf(g);
                }
            }
        asm volatile("s_waitcnt lgkmcnt(0)" ::: "memory");
        #pragma unroll
        for (int j = 0; j < 8; ++j) {
            const int chk = lane + j * 64;       // 512 chunks: 128 rows x 4 x 16B
            const int rr = chk >> 2, cc = chk & 3;
            short8 v = *(const short8*)(ws_ + rr * 40 + cc * 8);
            *(short8*)(h1 + (size_t)(ro + rr) * DFF_ + co + p * 32 + cc * 8) = v;
        }
        asm volatile("s_waitcnt lgkmcnt(0)" ::: "memory");
    }
}

// ---------------- MFMA GEMM 2: out[sel] = x_sel + h1 @ w2 + b2 (scattered, 64B-aligned stores) ----------------
__global__ __launch_bounds__(256) void ffn2_mfma_kernel(const unsigned short* __restrict__ A,
                                                        const unsigned short* __restrict__ Bt,
                                                        const float* __restrict__ b2,
                                                        const float* __restrict__ x,
                                                        const int* __restrict__ topk,
                                                        float* __restrict__ out) {
    constexpr int K = DFF_;               // 4096
    __shared__ __align__(16) unsigned short As[128 * 32];
    __shared__ __align__(16) unsigned short Bs[128 * 32];
    int t = threadIdx.x;
    int w = t >> 6, lane = t & 63;
    int quad = lane >> 4, lr = lane & 15;
    int wm = w >> 1, wn = w & 1;
    int row0 = blockIdx.x * 128, col0 = blockIdx.y * 128;

    const char* ga0 = (const char*)(A + (size_t)(row0 + (t >> 2)) * K) + (t & 3) * 16;
    const char* ga1 = ga0 + (size_t)64 * K * 2;
    const char* gb0 = (const char*)(Bt + (size_t)(col0 + (t >> 2)) * K) + (t & 3) * 16;
    const char* gb1 = gb0 + (size_t)64 * K * 2;
    unsigned short* la0 = As + t * 8;   unsigned short* la1 = As + 2048 + t * 8;
    unsigned short* lb0 = Bs + t * 8;   unsigned short* lb1 = Bs + 2048 + t * 8;

    float4v acc[4][4] = {};
    for (int k0 = 0; k0 < K; k0 += 32) {
        gld16(ga0, la0); gld16(ga1, la1);
        gld16(gb0, lb0); gld16(gb1, lb1);
        ga0 += 64; ga1 += 64; gb0 += 64; gb1 += 64;
        __syncthreads();
        short8 af[4], bfv[4];
        #pragma unroll
        for (int mi = 0; mi < 4; ++mi)
            af[mi] = *(const short8*)(As + (size_t)(wm * 64 + mi * 16 + lr) * 32 + quad * 8);
        #pragma unroll
        for (int ni = 0; ni < 4; ++ni)
            bfv[ni] = *(const short8*)(Bs + (size_t)(wn * 64 + ni * 16 + lr) * 32 + quad * 8);
        #pragma unroll
        for (int mi = 0; mi < 4; ++mi)
            #pragma unroll
            for (int ni = 0; ni < 4; ++ni)
                acc[mi][ni] = __builtin_amdgcn_mfma_f32_16x16x32_bf16(af[mi], bfv[ni], acc[mi][ni], 0, 0, 0);
        __syncthreads();
    }

    #pragma unroll
    for (int mi = 0; mi < 4; ++mi) {
        #pragma unroll
        for (int r = 0; r < 4; ++r) {
            int row = row0 + wm * 64 + mi * 16 + quad * 4 + r;
            int gb = row >> 11;
            int tok = topk[row];
            size_t base = ((size_t)(gb * N_ + tok)) * D_;
            #pragma unroll
            for (int ni = 0; ni < 4; ++ni) {
                int col = col0 + wn * 64 + ni * 16 + lr;
                out[base + col] = x[base + col] + acc[mi][ni][r] + b2[col];
            }
        }
    }
}

extern "C" void kernel_launch(void* const* d_in, const int* in_sizes, int n_in,
                              void* d_out, int out_size, void* d_ws, size_t ws_size,
                              hipStream_t stream) {
    const float* x      = (const float*)d_in[0];
    const float* gate_w = (const float*)d_in[1];
    const float* w1     = (const float*)d_in[2];
    const float* b1     = (const float*)d_in[3];
    const float* w2     = (const float*)d_in[4];
    const float* b2     = (const float*)d_in[5];
    float* out = (float*)d_out;

    char* ws = (char*)d_ws;
    float*          scores = (float*)ws;                                        // 64 KiB
    int*            topk   = (int*)(ws + (64 << 10));                           // 32 KiB
    int*            slot   = (int*)(ws + (96 << 10));                           // 64 KiB
    unsigned short* xsel   = (unsigned short*)(ws + (160 << 10));               // 16 MiB
    unsigned short* w1t    = (unsigned short*)(ws + (160 << 10) + (16 << 20));  // 8 MiB  [4096][1024]
    unsigned short* w2t    = (unsigned short*)(ws + (160 << 10) + (24 << 20));  // 8 MiB  [1024][4096]
    unsigned short* h1     = (unsigned short*)(ws + (160 << 10) + (32 << 20));  // 64 MiB [8192][4096]

    scores_kernel<<<(B_ * N_) / 4, 256, 0, stream>>>(x, gate_w, scores, slot);
    select_topk_kernel<<<B_, 1024, 0, stream>>>(scores, topk, slot);

    transpose_both_kernel<<<8192, 256, 0, stream>>>(w1, w2, w1t, w2t);

    gather_copy_kernel<<<B_ * N_, 256, 0, stream>>>(x, slot, xsel, out);

    ffn1_pipe_kernel<<<dim3(32, 16), 512, 0, stream>>>(xsel, w1t, b1, h1);
    ffn2_mfma_kernel<<<dim3(64, 8), 256, 0, stream>>>(h1, w2t, b2, x, topk, out);
}

// Round 2
// 335.399 us; speedup vs baseline: 1.0520x; 1.0383x over previous
//
#include <hip/hip_runtime.h>
#include <math.h>

#define B_   4
#define N_   4096
#define D_   1024
#define DFF_ 4096
#define K_   2048

typedef __attribute__((ext_vector_type(8))) short short8;
typedef __attribute__((ext_vector_type(4))) float float4v;

__device__ __forceinline__ unsigned short f2bf(float f) {
    unsigned int u = __float_as_uint(f);
    u = (u + 0x7fffu + ((u >> 16) & 1u)) >> 16;   // RNE
    return (unsigned short)u;
}

__device__ __forceinline__ void gld16(const void* g, void* l) {
    __builtin_amdgcn_global_load_lds((const __attribute__((address_space(1))) void*)g,
                                     (__attribute__((address_space(3))) void*)l, 16, 0, 0);
}

// ---------------- scores (bit-identical selection math) + slot clear ----------------
__global__ __launch_bounds__(256) void scores_kernel(const float* __restrict__ x,
                                                     const float* __restrict__ gate_w,
                                                     float* __restrict__ scores,
                                                     int* __restrict__ slot) {
    int wave = (blockIdx.x * blockDim.x + threadIdx.x) >> 6;
    int lane = threadIdx.x & 63;
    if (wave >= B_ * N_) return;
    if (lane == 1) slot[wave] = -1;
    const float4* xr = (const float4*)(x + (size_t)wave * D_);
    const float4* g  = (const float4*)gate_w;
    float acc = 0.f;
    #pragma unroll
    for (int j = 0; j < D_ / 4 / 64; ++j) {
        float4 a = xr[lane + j * 64];
        float4 b = g[lane + j * 64];
        acc += a.x * b.x + a.y * b.y + a.z * b.z + a.w * b.w;
    }
    #pragma unroll
    for (int off = 32; off > 0; off >>= 1) acc += __shfl_down(acc, off, 64);
    if (lane == 0) scores[wave] = acc;
}

// ---------------- top-k radix select, wave-level scans; writes topk + global slot map ----------------
__global__ __launch_bounds__(1024) void select_topk_kernel(const float* __restrict__ scores,
                                                           int* __restrict__ topk,
                                                           int* __restrict__ slot) {
    __shared__ unsigned key[N_];
    __shared__ unsigned hist[256];
    __shared__ int sh_bin, sh_rem, sh_ngt;
    __shared__ int wsum[16], woff[16];
    int b = blockIdx.x, tid = threadIdx.x;
    int lane = tid & 63, wid = tid >> 6;

    for (int i = tid; i < N_; i += 1024) {
        unsigned u = __float_as_uint(scores[b * N_ + i]);
        key[i] = (u & 0x80000000u) ? ~u : (u | 0x80000000u);   // monotonic map
    }
    if (tid == 0) sh_ngt = 0;
    __syncthreads();

    unsigned prefix = 0, pmask = 0;
    int rem = K_;
    for (int shift = 24; shift >= 0; shift -= 8) {
        if (tid < 256) hist[tid] = 0;
        __syncthreads();
        for (int i = tid; i < N_; i += 1024) {
            unsigned k = key[i];
            if ((k & pmask) == prefix) atomicAdd(&hist[(k >> shift) & 255u], 1u);
        }
        __syncthreads();
        if (tid < 64) {   // wave 0: suffix scan of 256 bins, 4 bins/lane
            unsigned v0 = hist[4 * lane], v1 = hist[4 * lane + 1];
            unsigned v2 = hist[4 * lane + 2], v3 = hist[4 * lane + 3];
            unsigned s3 = v3, s2 = v2 + s3, s1 = v1 + s2, s0 = v0 + s1;
            unsigned t = s0;
            #pragma unroll
            for (int off = 1; off < 64; off <<= 1) {
                unsigned u = __shfl_down(t, off, 64);
                if (lane + off < 64) t += u;
            }
            unsigned above = t - s0;                  // keys in bins > 4*lane+3
            unsigned S0 = s0 + above, S1 = s1 + above, S2 = s2 + above, S3 = s3 + above;
            unsigned R = (unsigned)rem;
            if (S0 >= R && S1 < R) { sh_bin = 4 * lane;     sh_rem = rem - (int)S1; }
            if (S1 >= R && S2 < R) { sh_bin = 4 * lane + 1; sh_rem = rem - (int)S2; }
            if (S2 >= R && S3 < R) { sh_bin = 4 * lane + 2; sh_rem = rem - (int)S3; }
            if (S3 >= R && above < R) { sh_bin = 4 * lane + 3; sh_rem = rem - (int)above; }
        }
        __syncthreads();
        prefix |= ((unsigned)sh_bin) << shift;
        pmask  |= 0xffu << shift;
        rem = sh_rem;
    }
    unsigned T = prefix;          // exact key of k-th largest
    int c_gt = K_ - rem;          // count strictly greater

    // strictly-greater: ballot-compacted, arbitrary order, slots [0, c_gt)
    for (int i = tid; i < N_; i += 1024) {
        bool p = key[i] > T;
        unsigned long long m = __ballot(p);
        int cnt = __popcll(m);
        int basepos = 0;
        if (lane == 0 && cnt) basepos = atomicAdd(&sh_ngt, cnt);
        basepos = __shfl(basepos, 0, 64);
        if (p) {
            int pos = basepos + __popcll(m & ((1ULL << lane) - 1ULL));
            topk[b * K_ + pos] = i;
            slot[b * N_ + i] = b * K_ + pos;
        }
    }
    // ties: first `rem` by index -> slots [c_gt, K)
    int base = tid * 4, c = 0;
    #pragma unroll
    for (int j = 0; j < 4; ++j) c += (key[base + j] == T);
    int sc = c;
    #pragma unroll
    for (int off = 1; off < 64; off <<= 1) {
        int u = __shfl_up(sc, off, 64);
        if (lane >= off) sc += u;
    }
    if (lane == 63) wsum[wid] = sc;
    __syncthreads();
    if (tid == 0) {
        int run = 0;
        #pragma unroll
        for (int j = 0; j < 16; ++j) { woff[j] = run; run += wsum[j]; }
    }
    __syncthreads();
    int r = woff[wid] + sc - c;   // exclusive prefix among ties
    #pragma unroll
    for (int j = 0; j < 4; ++j) {
        if (key[base + j] == T) {
            if (r < rem) {
                topk[b * K_ + c_gt + r] = base + j;
                slot[b * N_ + base + j] = b * K_ + c_gt + r;
            }
            ++r;
        }
    }
}

// ---------------- fused: selected rows -> bf16 xsel[slot]; unselected -> out copy ----------------
__global__ __launch_bounds__(256) void gather_copy_kernel(const float* __restrict__ x,
                                                          const int* __restrict__ slot,
                                                          unsigned short* __restrict__ xsel,
                                                          float* __restrict__ out) {
    int row = blockIdx.x;
    int t = threadIdx.x;
    int s = slot[row];
    float4 v = ((const float4*)(x + (size_t)row * D_))[t];
    if (s >= 0) {
        ushort4 o;
        o.x = f2bf(v.x); o.y = f2bf(v.y); o.z = f2bf(v.z); o.w = f2bf(v.w);
        ((ushort4*)(xsel + (size_t)s * D_))[t] = o;
    } else {
        ((float4*)(out + (size_t)row * D_))[t] = v;
    }
}

// ---------------- both weight transposes (fp32 [R][C] -> bf16 [C][R]) in one launch ----------------
__global__ __launch_bounds__(256) void transpose_both_kernel(const float* __restrict__ w1,
                                                             const float* __restrict__ w2,
                                                             unsigned short* __restrict__ w1t,
                                                             unsigned short* __restrict__ w2t) {
    __shared__ float tile[32][33];
    int bid = blockIdx.x;
    const float* src; unsigned short* dst; int R, C, bx, by;
    if (bid < 4096) { src = w1; dst = w1t; R = D_;   C = DFF_; bx = bid & 127;          by = bid >> 7; }
    else            { src = w2; dst = w2t; R = DFF_; C = D_;   bx = (bid - 4096) & 31;  by = (bid - 4096) >> 5; }
    int tx = threadIdx.x & 31, ty = threadIdx.x >> 5;   // 32 x 8
    int c = bx * 32 + tx, r0 = by * 32;
    #pragma unroll
    for (int j = ty; j < 32; j += 8) tile[j][tx] = src[(size_t)(r0 + j) * C + c];
    __syncthreads();
    int dc = by * 32 + tx, dr0 = bx * 32;
    #pragma unroll
    for (int j = ty; j < 32; j += 8) dst[(size_t)(dr0 + j) * R + dc] = f2bf(tile[tx][j]);
}

// ======== row-pair XOR swizzle (conflict-free LDS, coalesced staging) ========
// Region = rows of 32 shorts (4 x 16B chunks). Logical chunk (r, kc) stored at
// chunk index (r>>1)*8 + ((((r&1)<<2)|kc) ^ ((r>>1)&7)).
// - Fragment read (8 lanes: fixed kc=quad, 8 consecutive rows): bank-slots = kc^{0..7}, all distinct.
// - Staging (linear thread->chunk): each 8-lane group covers two full 64B rows (permuted) -> coalesced.

// ---------------- MFMA GEMM 1 (pipelined): h1 = gelu(x_sel @ w1 + b1) ----------------
// 256x256 tile, BK=32, 512 threads (8 waves, 2Mx4N), ring of 4 K-tile LDS buffers,
// staged 3 tiles ahead via global_load_lds; counted vmcnt(8) once per K-tile.
__global__ __launch_bounds__(512, 2) void ffn1_pipe_kernel(const unsigned short* __restrict__ A,
                                                           const unsigned short* __restrict__ Bt,
                                                           const float* __restrict__ b1,
                                                           unsigned short* __restrict__ h1) {
    constexpr int K  = D_;        // 1024
    constexpr int NT = K / 32;    // 32 K-tiles
    __shared__ __align__(16) unsigned short smem[65536];   // 4 x (A 8192 + B 8192 shorts) = 128 KiB

    const int t    = threadIdx.x;
    const int lane = t & 63;
    const int wid  = t >> 6;
    const int quad = lane >> 4;
    const int lr   = lane & 15;
    const int wr   = wid >> 2;            // 0..1  (M)
    const int wc   = wid & 3;             // 0..3  (N)
    const int row0 = blockIdx.x * 256;
    const int col0 = blockIdx.y * 256;

    // staging: thread t owns chunks t and t+512 of each 1024-chunk region; LDS dest LINEAR.
    const int ch0 = t, ch1 = t + 512;
    const int rp0 = ch0 >> 3, w0 = (ch0 & 7) ^ (rp0 & 7);
    const int rp1 = ch1 >> 3, w1 = (ch1 & 7) ^ (rp1 & 7);
    const int gr0 = rp0 * 2 + (w0 >> 2), gc0 = w0 & 3;
    const int gr1 = rp1 * 2 + (w1 >> 2), gc1 = w1 & 3;
    const char* aS0 = (const char*)A  + ((size_t)(row0 + gr0) * K + (size_t)gc0 * 8) * 2;
    const char* aS1 = (const char*)A  + ((size_t)(row0 + gr1) * K + (size_t)gc1 * 8) * 2;
    const char* bS0 = (const char*)Bt + ((size_t)(col0 + gr0) * K + (size_t)gc0 * 8) * 2;
    const char* bS1 = (const char*)Bt + ((size_t)(col0 + gr1) * K + (size_t)gc1 * 8) * 2;
    const int oA0 = ch0 * 8, oA1 = ch1 * 8;             // short offsets in buffer
    const int oB0 = 8192 + ch0 * 8, oB1 = 8192 + ch1 * 8;

    // fragment bases (swizzled); frag mi/ni advances 16 rows = +512 shorts (mod-8 invariant)
    const int rbA = wr * 128 + lr, rA2 = rbA >> 1;
    const int aoff = (rA2 * 8 + ((((rbA & 1) << 2) | quad) ^ (rA2 & 7))) * 8;
    const int rbB = wc * 64 + lr, rB2 = rbB >> 1;
    const int boff = 8192 + (rB2 * 8 + ((((rbB & 1) << 2) | quad) ^ (rB2 & 7))) * 8;

    // ---- prologue: stage K-tiles 0,1,2 into ring bufs 0,1,2 ----
    #pragma unroll
    for (int pt = 0; pt < 3; ++pt) {
        unsigned short* buf = smem + pt * 16384;
        gld16(aS0, buf + oA0); gld16(aS1, buf + oA1);
        gld16(bS0, buf + oB0); gld16(bS1, buf + oB1);
        aS0 += 64; aS1 += 64; bS0 += 64; bS1 += 64;
    }
    asm volatile("s_waitcnt vmcnt(8)" ::: "memory");   // tile 0 landed; tiles 1,2 in flight
    __builtin_amdgcn_s_barrier();

    float4v acc[8][4] = {};
    short8 af[8], bq[4];

    #pragma unroll 4
    for (int kt = 0; kt < NT; ++kt) {
        unsigned short* cur = smem + (kt & 3) * 16384;
        unsigned short* nxt = smem + ((kt + 3) & 3) * 16384;
        const bool pf = (kt + 3 < NT);

        // ---------- phase A: frags mi 0-3 + all B frags; stage A-half of tile kt+3 ----------
        #pragma unroll
        for (int mi = 0; mi < 4; ++mi) af[mi] = *(const short8*)(cur + aoff + mi * 512);
        #pragma unroll
        for (int ni = 0; ni < 4; ++ni) bq[ni] = *(const short8*)(cur + boff + ni * 512);
        if (pf) { gld16(aS0, nxt + oA0); gld16(aS1, nxt + oA1); }
        __builtin_amdgcn_s_barrier();
        __builtin_amdgcn_s_setprio(1);
        #pragma unroll
        for (int mi = 0; mi < 4; ++mi)
            #pragma unroll
            for (int ni = 0; ni < 4; ++ni)
                acc[mi][ni] = __builtin_amdgcn_mfma_f32_16x16x32_bf16(af[mi], bq[ni], acc[mi][ni], 0, 0, 0);
        __builtin_amdgcn_s_setprio(0);
        __builtin_amdgcn_s_barrier();

        // ---------- phase B: frags mi 4-7 (B reused); stage B-half of tile kt+3 ----------
        #pragma unroll
        for (int mi = 4; mi < 8; ++mi) af[mi] = *(const short8*)(cur + aoff + mi * 512);
        if (pf) { gld16(bS0, nxt + oB0); gld16(bS1, nxt + oB1); }
        aS0 += 64; aS1 += 64; bS0 += 64; bS1 += 64;
        // counted vmcnt: allow tiles kt+2,kt+3 (8 loads) in flight; guarantees kt+1 landed.
        if (kt < NT - 3)       asm volatile("s_waitcnt vmcnt(8)" ::: "memory");
        else if (kt == NT - 3) asm volatile("s_waitcnt vmcnt(4)" ::: "memory");
        else                   asm volatile("s_waitcnt vmcnt(0)" ::: "memory");
        __builtin_amdgcn_s_barrier();
        __builtin_amdgcn_s_setprio(1);
        #pragma unroll
        for (int mi = 4; mi < 8; ++mi)
            #pragma unroll
            for (int ni = 0; ni < 4; ++ni)
                acc[mi][ni] = __builtin_amdgcn_mfma_f32_16x16x32_bf16(af[mi], bq[ni], acc[mi][ni], 0, 0, 0);
        __builtin_amdgcn_s_setprio(0);
        __builtin_amdgcn_s_barrier();
    }

    // ---- epilogue: bias+GELU -> bf16 via per-wave-private LDS (128 rows x 40 shorts), 2 col-half passes ----
    float bias[4];
    #pragma unroll
    for (int ni = 0; ni < 4; ++ni) bias[ni] = b1[col0 + wc * 64 + ni * 16 + lr];
    unsigned short* ws_ = smem + wid * 5120;
    const int ro = row0 + wr * 128;
    const int co = col0 + wc * 64;
    #pragma unroll
    for (int p = 0; p < 2; ++p) {
        #pragma unroll
        for (int mi = 0; mi < 8; ++mi)
            #pragma unroll
            for (int nj = 0; nj < 2; ++nj) {
                const int ni = p * 2 + nj;
                #pragma unroll
                for (int r = 0; r < 4; ++r) {
                    float u = acc[mi][ni][r] + bias[ni];
                    float tt = 1.5957691216057308f * u * (1.0f + 0.044715f * u * u);
                    float g = u / (1.0f + __expf(-tt));
                    ws_[(mi * 16 + quad * 4 + r) * 40 + nj * 16 + lr] = f2bf(g);
                }
            }
        asm volatile("s_waitcnt lgkmcnt(0)" ::: "memory");
        #pragma unroll
        for (int j = 0; j < 8; ++j) {
            const int chk = lane + j * 64;       // 512 chunks: 128 rows x 4 x 16B
            const int rr = chk >> 2, cc = chk & 3;
            short8 v = *(const short8*)(ws_ + rr * 40 + cc * 8);
            *(short8*)(h1 + (size_t)(ro + rr) * DFF_ + co + p * 32 + cc * 8) = v;
        }
        asm volatile("s_waitcnt lgkmcnt(0)" ::: "memory");
    }
}

// ---------------- MFMA GEMM 2 (pipelined): out[sel] = x_sel + h1 @ w2 + b2 ----------------
// 128x256 tile, BK=32, 512 threads (8 waves, 2Mx4N -> 64x64/wave), ring-4 (96 KiB),
// counted vmcnt(6) (3 loads/tile); same row-pair swizzle; scattered fp32 epilogue.
__global__ __launch_bounds__(512, 2) void ffn2_pipe_kernel(const unsigned short* __restrict__ A,
                                                           const unsigned short* __restrict__ Bt,
                                                           const float* __restrict__ b2,
                                                           const float* __restrict__ x,
                                                           const int* __restrict__ topk,
                                                           float* __restrict__ out) {
    constexpr int K  = DFF_;      // 4096
    constexpr int NT = K / 32;    // 128 K-tiles
    __shared__ __align__(16) unsigned short smem[49152];   // 4 x (A 4096 + B 8192 shorts) = 96 KiB

    const int t    = threadIdx.x;
    const int lane = t & 63;
    const int wid  = t >> 6;
    const int quad = lane >> 4;
    const int lr   = lane & 15;
    const int wr   = wid >> 2;            // 0..1  (M, 64 rows)
    const int wc   = wid & 3;             // 0..3  (N, 64 cols)
    const int row0 = blockIdx.x * 128;
    const int col0 = blockIdx.y * 256;

    // staging: A 512 chunks (thread t -> ch t), B 1024 chunks (t -> ch t, t+512)
    const int chA = t;
    const int rpa = chA >> 3, wa = (chA & 7) ^ (rpa & 7);
    const char* aS = (const char*)A + ((size_t)(row0 + rpa * 2 + (wa >> 2)) * K + (size_t)(wa & 3) * 8) * 2;
    const int ch0 = t, ch1 = t + 512;
    const int rp0 = ch0 >> 3, w0 = (ch0 & 7) ^ (rp0 & 7);
    const int rp1 = ch1 >> 3, w1 = (ch1 & 7) ^ (rp1 & 7);
    const char* bS0 = (const char*)Bt + ((size_t)(col0 + rp0 * 2 + (w0 >> 2)) * K + (size_t)(w0 & 3) * 8) * 2;
    const char* bS1 = (const char*)Bt + ((size_t)(col0 + rp1 * 2 + (w1 >> 2)) * K + (size_t)(w1 & 3) * 8) * 2;
    const int oA = chA * 8;
    const int oB0 = 4096 + ch0 * 8, oB1 = 4096 + ch1 * 8;

    const int rbA = wr * 64 + lr, rA2 = rbA >> 1;
    const int aoff = (rA2 * 8 + ((((rbA & 1) << 2) | quad) ^ (rA2 & 7))) * 8;
    const int rbB = wc * 64 + lr, rB2 = rbB >> 1;
    const int boff = 4096 + (rB2 * 8 + ((((rbB & 1) << 2) | quad) ^ (rB2 & 7))) * 8;

    // ---- prologue: stage K-tiles 0,1,2 ----
    #pragma unroll
    for (int pt = 0; pt < 3; ++pt) {
        unsigned short* buf = smem + pt * 12288;
        gld16(aS, buf + oA); gld16(bS0, buf + oB0); gld16(bS1, buf + oB1);
        aS += 64; bS0 += 64; bS1 += 64;
    }
    asm volatile("s_waitcnt vmcnt(6)" ::: "memory");   // tile 0 landed
    __builtin_amdgcn_s_barrier();

    float4v acc[4][4] = {};
    short8 af[4], bq[4];

    #pragma unroll 4
    for (int kt = 0; kt < NT; ++kt) {
        unsigned short* cur = smem + (kt & 3) * 12288;
        unsigned short* nxt = smem + ((kt + 3) & 3) * 12288;
        const bool pf = (kt + 3 < NT);

        // ---------- phase A: frags mi 0-1 + all B frags; stage A + B-half0 of tile kt+3 ----------
        af[0] = *(const short8*)(cur + aoff);
        af[1] = *(const short8*)(cur + aoff + 512);
        #pragma unroll
        for (int ni = 0; ni < 4; ++ni) bq[ni] = *(const short8*)(cur + boff + ni * 512);
        if (pf) { gld16(aS, nxt + oA); gld16(bS0, nxt + oB0); }
        __builtin_amdgcn_s_barrier();
        __builtin_amdgcn_s_setprio(1);
        #pragma unroll
        for (int mi = 0; mi < 2; ++mi)
            #pragma unroll
            for (int ni = 0; ni < 4; ++ni)
                acc[mi][ni] = __builtin_amdgcn_mfma_f32_16x16x32_bf16(af[mi], bq[ni], acc[mi][ni], 0, 0, 0);
        __builtin_amdgcn_s_setprio(0);
        __builtin_amdgcn_s_barrier();

        // ---------- phase B: frags mi 2-3; stage B-half1 of tile kt+3 ----------
        af[2] = *(const short8*)(cur + aoff + 1024);
        af[3] = *(const short8*)(cur + aoff + 1536);
        if (pf) { gld16(bS1, nxt + oB1); }
        aS += 64; bS0 += 64; bS1 += 64;
        // counted vmcnt: allow tiles kt+2,kt+3 (6 loads) in flight; guarantees kt+1 landed.
        if (kt < NT - 3)       asm volatile("s_waitcnt vmcnt(6)" ::: "memory");
        else if (kt == NT - 3) asm volatile("s_waitcnt vmcnt(3)" ::: "memory");
        else                   asm volatile("s_waitcnt vmcnt(0)" ::: "memory");
        __builtin_amdgcn_s_barrier();
        __builtin_amdgcn_s_setprio(1);
        #pragma unroll
        for (int mi = 2; mi < 4; ++mi)
            #pragma unroll
            for (int ni = 0; ni < 4; ++ni)
                acc[mi][ni] = __builtin_amdgcn_mfma_f32_16x16x32_bf16(af[mi], bq[ni], acc[mi][ni], 0, 0, 0);
        __builtin_amdgcn_s_setprio(0);
        __builtin_amdgcn_s_barrier();
    }

    // ---- epilogue: scattered residual stores (identical math/order to previous ffn2) ----
    #pragma unroll
    for (int mi = 0; mi < 4; ++mi) {
        #pragma unroll
        for (int r = 0; r < 4; ++r) {
            int row = row0 + wr * 64 + mi * 16 + quad * 4 + r;
            int gb = row >> 11;
            int tok = topk[row];
            size_t base = ((size_t)(gb * N_ + tok)) * D_;
            #pragma unroll
            for (int ni = 0; ni < 4; ++ni) {
                int col = col0 + wc * 64 + ni * 16 + lr;
                out[base + col] = x[base + col] + acc[mi][ni][r] + b2[col];
            }
        }
    }
}

extern "C" void kernel_launch(void* const* d_in, const int* in_sizes, int n_in,
                              void* d_out, int out_size, void* d_ws, size_t ws_size,
                              hipStream_t stream) {
    const float* x      = (const float*)d_in[0];
    const float* gate_w = (const float*)d_in[1];
    const float* w1     = (const float*)d_in[2];
    const float* b1     = (const float*)d_in[3];
    const float* w2     = (const float*)d_in[4];
    const float* b2     = (const float*)d_in[5];
    float* out = (float*)d_out;

    char* ws = (char*)d_ws;
    float*          scores = (float*)ws;                                        // 64 KiB
    int*            topk   = (int*)(ws + (64 << 10));                           // 32 KiB
    int*            slot   = (int*)(ws + (96 << 10));                           // 64 KiB
    unsigned short* xsel   = (unsigned short*)(ws + (160 << 10));               // 16 MiB
    unsigned short* w1t    = (unsigned short*)(ws + (160 << 10) + (16 << 20));  // 8 MiB  [4096][1024]
    unsigned short* w2t    = (unsigned short*)(ws + (160 << 10) + (24 << 20));  // 8 MiB  [1024][4096]
    unsigned short* h1     = (unsigned short*)(ws + (160 << 10) + (32 << 20));  // 64 MiB [8192][4096]

    scores_kernel<<<(B_ * N_) / 4, 256, 0, stream>>>(x, gate_w, scores, slot);
    select_topk_kernel<<<B_, 1024, 0, stream>>>(scores, topk, slot);

    transpose_both_kernel<<<8192, 256, 0, stream>>>(w1, w2, w1t, w2t);

    gather_copy_kernel<<<B_ * N_, 256, 0, stream>>>(x, slot, xsel, out);

    ffn1_pipe_kernel<<<dim3(32, 16), 512, 0, stream>>>(xsel, w1t, b1, h1);
    ffn2_pipe_kernel<<<dim3(64, 4), 512, 0, stream>>>(h1, w2t, b2, x, topk, out);
}

// Round 3
// 329.787 us; speedup vs baseline: 1.0699x; 1.0170x over previous
//
#include <hip/hip_runtime.h>
#include <math.h>

#define B_   4
#define N_   4096
#define D_   1024
#define DFF_ 4096
#define K_   2048

typedef __attribute__((ext_vector_type(8))) short short8;
typedef __attribute__((ext_vector_type(4))) float float4v;

__device__ __forceinline__ unsigned short f2bf(float f) {
    unsigned int u = __float_as_uint(f);
    u = (u + 0x7fffu + ((u >> 16) & 1u)) >> 16;   // RNE
    return (unsigned short)u;
}

__device__ __forceinline__ void gld16(const void* g, void* l) {
    __builtin_amdgcn_global_load_lds((const __attribute__((address_space(1))) void*)g,
                                     (__attribute__((address_space(3))) void*)l, 16, 0, 0);
}

// ---------------- scores (bit-identical selection math) + slot clear ----------------
__global__ __launch_bounds__(256) void scores_kernel(const float* __restrict__ x,
                                                     const float* __restrict__ gate_w,
                                                     float* __restrict__ scores,
                                                     int* __restrict__ slot) {
    int wave = (blockIdx.x * blockDim.x + threadIdx.x) >> 6;
    int lane = threadIdx.x & 63;
    if (wave >= B_ * N_) return;
    if (lane == 1) slot[wave] = -1;
    const float4* xr = (const float4*)(x + (size_t)wave * D_);
    const float4* g  = (const float4*)gate_w;
    float acc = 0.f;
    #pragma unroll
    for (int j = 0; j < D_ / 4 / 64; ++j) {
        float4 a = xr[lane + j * 64];
        float4 b = g[lane + j * 64];
        acc += a.x * b.x + a.y * b.y + a.z * b.z + a.w * b.w;
    }
    #pragma unroll
    for (int off = 32; off > 0; off >>= 1) acc += __shfl_down(acc, off, 64);
    if (lane == 0) scores[wave] = acc;
}

// ---------------- top-k radix select, wave-level scans; writes topk + global slot map ----------------
__global__ __launch_bounds__(1024) void select_topk_kernel(const float* __restrict__ scores,
                                                           int* __restrict__ topk,
                                                           int* __restrict__ slot) {
    __shared__ unsigned key[N_];
    __shared__ unsigned hist[256];
    __shared__ int sh_bin, sh_rem, sh_ngt;
    __shared__ int wsum[16], woff[16];
    int b = blockIdx.x, tid = threadIdx.x;
    int lane = tid & 63, wid = tid >> 6;

    for (int i = tid; i < N_; i += 1024) {
        unsigned u = __float_as_uint(scores[b * N_ + i]);
        key[i] = (u & 0x80000000u) ? ~u : (u | 0x80000000u);   // monotonic map
    }
    if (tid == 0) sh_ngt = 0;
    __syncthreads();

    unsigned prefix = 0, pmask = 0;
    int rem = K_;
    for (int shift = 24; shift >= 0; shift -= 8) {
        if (tid < 256) hist[tid] = 0;
        __syncthreads();
        for (int i = tid; i < N_; i += 1024) {
            unsigned k = key[i];
            if ((k & pmask) == prefix) atomicAdd(&hist[(k >> shift) & 255u], 1u);
        }
        __syncthreads();
        if (tid < 64) {   // wave 0: suffix scan of 256 bins, 4 bins/lane
            unsigned v0 = hist[4 * lane], v1 = hist[4 * lane + 1];
            unsigned v2 = hist[4 * lane + 2], v3 = hist[4 * lane + 3];
            unsigned s3 = v3, s2 = v2 + s3, s1 = v1 + s2, s0 = v0 + s1;
            unsigned t = s0;
            #pragma unroll
            for (int off = 1; off < 64; off <<= 1) {
                unsigned u = __shfl_down(t, off, 64);
                if (lane + off < 64) t += u;
            }
            unsigned above = t - s0;                  // keys in bins > 4*lane+3
            unsigned S0 = s0 + above, S1 = s1 + above, S2 = s2 + above, S3 = s3 + above;
            unsigned R = (unsigned)rem;
            if (S0 >= R && S1 < R) { sh_bin = 4 * lane;     sh_rem = rem - (int)S1; }
            if (S1 >= R && S2 < R) { sh_bin = 4 * lane + 1; sh_rem = rem - (int)S2; }
            if (S2 >= R && S3 < R) { sh_bin = 4 * lane + 2; sh_rem = rem - (int)S3; }
            if (S3 >= R && above < R) { sh_bin = 4 * lane + 3; sh_rem = rem - (int)above; }
        }
        __syncthreads();
        prefix |= ((unsigned)sh_bin) << shift;
        pmask  |= 0xffu << shift;
        rem = sh_rem;
    }
    unsigned T = prefix;          // exact key of k-th largest
    int c_gt = K_ - rem;          // count strictly greater

    // strictly-greater: ballot-compacted, arbitrary order, slots [0, c_gt)
    for (int i = tid; i < N_; i += 1024) {
        bool p = key[i] > T;
        unsigned long long m = __ballot(p);
        int cnt = __popcll(m);
        int basepos = 0;
        if (lane == 0 && cnt) basepos = atomicAdd(&sh_ngt, cnt);
        basepos = __shfl(basepos, 0, 64);
        if (p) {
            int pos = basepos + __popcll(m & ((1ULL << lane) - 1ULL));
            topk[b * K_ + pos] = i;
            slot[b * N_ + i] = b * K_ + pos;
        }
    }
    // ties: first `rem` by index -> slots [c_gt, K)
    int base = tid * 4, c = 0;
    #pragma unroll
    for (int j = 0; j < 4; ++j) c += (key[base + j] == T);
    int sc = c;
    #pragma unroll
    for (int off = 1; off < 64; off <<= 1) {
        int u = __shfl_up(sc, off, 64);
        if (lane >= off) sc += u;
    }
    if (lane == 63) wsum[wid] = sc;
    __syncthreads();
    if (tid == 0) {
        int run = 0;
        #pragma unroll
        for (int j = 0; j < 16; ++j) { woff[j] = run; run += wsum[j]; }
    }
    __syncthreads();
    int r = woff[wid] + sc - c;   // exclusive prefix among ties
    #pragma unroll
    for (int j = 0; j < 4; ++j) {
        if (key[base + j] == T) {
            if (r < rem) {
                topk[b * K_ + c_gt + r] = base + j;
                slot[b * N_ + base + j] = b * K_ + c_gt + r;
            }
            ++r;
        }
    }
}

// ---------------- fused: selected rows -> bf16 xsel[slot]; unselected -> out copy ----------------
__global__ __launch_bounds__(256) void gather_copy_kernel(const float* __restrict__ x,
                                                          const int* __restrict__ slot,
                                                          unsigned short* __restrict__ xsel,
                                                          float* __restrict__ out) {
    int row = blockIdx.x;
    int t = threadIdx.x;
    int s = slot[row];
    float4 v = ((const float4*)(x + (size_t)row * D_))[t];
    if (s >= 0) {
        ushort4 o;
        o.x = f2bf(v.x); o.y = f2bf(v.y); o.z = f2bf(v.z); o.w = f2bf(v.w);
        ((ushort4*)(xsel + (size_t)s * D_))[t] = o;
    } else {
        ((float4*)(out + (size_t)row * D_))[t] = v;
    }
}

// ---------------- both weight transposes (fp32 [R][C] -> bf16 [C][R]) in one launch ----------------
__global__ __launch_bounds__(256) void transpose_both_kernel(const float* __restrict__ w1,
                                                             const float* __restrict__ w2,
                                                             unsigned short* __restrict__ w1t,
                                                             unsigned short* __restrict__ w2t) {
    __shared__ float tile[32][33];
    int bid = blockIdx.x;
    const float* src; unsigned short* dst; int R, C, bx, by;
    if (bid < 4096) { src = w1; dst = w1t; R = D_;   C = DFF_; bx = bid & 127;          by = bid >> 7; }
    else            { src = w2; dst = w2t; R = DFF_; C = D_;   bx = (bid - 4096) & 31;  by = (bid - 4096) >> 5; }
    int tx = threadIdx.x & 31, ty = threadIdx.x >> 5;   // 32 x 8
    int c = bx * 32 + tx, r0 = by * 32;
    #pragma unroll
    for (int j = ty; j < 32; j += 8) tile[j][tx] = src[(size_t)(r0 + j) * C + c];
    __syncthreads();
    int dc = by * 32 + tx, dr0 = bx * 32;
    #pragma unroll
    for (int j = ty; j < 32; j += 8) dst[(size_t)(dr0 + j) * R + dc] = f2bf(tile[tx][j]);
}

// ======== row-pair XOR swizzle (verified r2: conflicts 6.8M -> 0.5M) ========
// Region = rows of 32 shorts (4 x 16B chunks). Logical chunk (r, kc) stored at
// chunk index (r>>1)*8 + ((((r&1)<<2)|kc) ^ ((r>>1)&7)). LDS dest stays linear
// for global_load_lds; the permutation is applied to the global source address
// and to the ds_read address (same involution both sides).

// ---------------- MFMA GEMM 1 (2 blocks/CU): h1 = gelu(x_sel @ w1 + b1) ----------------
// 256x128 tile, BK=32, 512 thr (8 waves 4Mx2N, 64x64/wave), double-buffer 48 KiB,
// ONE barrier + ONE vmcnt(0) per K-tile (vmcnt hidden under MFMA; cross-block overlap
// via 2 resident blocks/CU). Epilogue: full-128B-line h1 stores (no partial-line RMW).
__global__ __launch_bounds__(512, 4) void ffn1_db_kernel(const unsigned short* __restrict__ A,
                                                         const unsigned short* __restrict__ Bt,
                                                         const float* __restrict__ b1,
                                                         unsigned short* __restrict__ h1) {
    constexpr int K  = D_;        // 1024
    constexpr int NT = K / 32;    // 32 K-tiles
    __shared__ __align__(16) unsigned short smem[24576];   // 48 KiB: 2 x (A 8192 | B 4096 shorts)

    const int t    = threadIdx.x;
    const int lane = t & 63;
    const int wid  = t >> 6;
    const int quad = lane >> 4;
    const int lr   = lane & 15;
    const int wr   = wid >> 1;            // 0..3  (M)
    const int wc   = wid & 1;             // 0..1  (N)
    const int row0 = blockIdx.x * 256;
    const int col0 = blockIdx.y * 128;

    // staging: A = 1024 chunks (thread t -> ch t, t+512), B = 512 chunks (-> ch t)
    const int chA0 = t, chA1 = t + 512, chB = t;
    const int rpA0 = chA0 >> 3, wA0 = (chA0 & 7) ^ (rpA0 & 7);
    const int rpA1 = chA1 >> 3, wA1 = (chA1 & 7) ^ (rpA1 & 7);
    const int rpB  = chB  >> 3, wB  = (chB  & 7) ^ (rpB  & 7);
    const char* aS0 = (const char*)A  + ((size_t)(row0 + rpA0 * 2 + (wA0 >> 2)) * K + (size_t)(wA0 & 3) * 8) * 2;
    const char* aS1 = (const char*)A  + ((size_t)(row0 + rpA1 * 2 + (wA1 >> 2)) * K + (size_t)(wA1 & 3) * 8) * 2;
    const char* bS  = (const char*)Bt + ((size_t)(col0 + rpB  * 2 + (wB  >> 2)) * K + (size_t)(wB  & 3) * 8) * 2;
    const int oA0 = chA0 * 8, oA1 = chA1 * 8, oB = 8192 + chB * 8;

    // fragment bases (swizzled); frag advance 16 rows = +512 shorts (row-pair mod-8 invariant)
    const int rbA = wr * 64 + lr, rA2 = rbA >> 1;
    const int aoff = (rA2 * 8 + ((((rbA & 1) << 2) | quad) ^ (rA2 & 7))) * 8;
    const int rbB = wc * 64 + lr, rB2 = rbB >> 1;
    const int boff = 8192 + (rB2 * 8 + ((((rbB & 1) << 2) | quad) ^ (rB2 & 7))) * 8;

    unsigned short* lds0 = smem;
    unsigned short* lds1 = smem + 12288;

    // ---- prologue: stage K-tile 0 ----
    gld16(aS0, lds0 + oA0); gld16(aS1, lds0 + oA1); gld16(bS, lds0 + oB);
    aS0 += 64; aS1 += 64; bS += 64;
    asm volatile("s_waitcnt vmcnt(0)" ::: "memory");
    __builtin_amdgcn_s_barrier();

    float4v acc[4][4] = {};
    short8 af[4], bq[4];

    auto step = [&](const unsigned short* cur, unsigned short* nxt, bool pf) {
        #pragma unroll
        for (int mi = 0; mi < 4; ++mi) af[mi] = *(const short8*)(cur + aoff + mi * 512);
        #pragma unroll
        for (int ni = 0; ni < 4; ++ni) bq[ni] = *(const short8*)(cur + boff + ni * 512);
        if (pf) {
            gld16(aS0, nxt + oA0); gld16(aS1, nxt + oA1); gld16(bS, nxt + oB);
            aS0 += 64; aS1 += 64; bS += 64;
        }
        __builtin_amdgcn_sched_barrier(0);
        __builtin_amdgcn_s_setprio(1);
        #pragma unroll
        for (int mi = 0; mi < 4; ++mi)
            #pragma unroll
            for (int ni = 0; ni < 4; ++ni)
                acc[mi][ni] = __builtin_amdgcn_mfma_f32_16x16x32_bf16(af[mi], bq[ni], acc[mi][ni], 0, 0, 0);
        __builtin_amdgcn_s_setprio(0);
        asm volatile("s_waitcnt vmcnt(0)" ::: "memory");   // next tile landed (hidden under MFMA)
        __builtin_amdgcn_s_barrier();
    };

    for (int kt = 0; kt < NT - 2; kt += 2) { step(lds0, lds1, true); step(lds1, lds0, true); }
    step(lds0, lds1, true);    // kt = NT-2
    step(lds1, lds0, false);   // kt = NT-1 (no prefetch; trailing barrier guards smem reuse)

    // ---- epilogue: bias+GELU -> bf16 via per-wave LDS (16 rows x 66 shorts), full-line stores ----
    float bias[4];
    #pragma unroll
    for (int ni = 0; ni < 4; ++ni) bias[ni] = b1[col0 + wc * 64 + ni * 16 + lr];
    unsigned short* ws_ = smem + wid * 1056;   // 8 waves x 1056 shorts = 16.5 KiB
    const int ro = row0 + wr * 64, co = col0 + wc * 64;
    #pragma unroll
    for (int mi = 0; mi < 4; ++mi) {
        #pragma unroll
        for (int ni = 0; ni < 4; ++ni)
            #pragma unroll
            for (int r = 0; r < 4; ++r) {
                float u = acc[mi][ni][r] + bias[ni];
                float tt = 1.5957691216057308f * u * (1.0f + 0.044715f * u * u);
                float g = u / (1.0f + __expf(-tt));
                ws_[(quad * 4 + r) * 66 + ni * 16 + lr] = f2bf(g);
            }
        asm volatile("s_waitcnt lgkmcnt(0)" ::: "memory");
        #pragma unroll
        for (int j = 0; j < 2; ++j) {
            int chk = lane + j * 64;          // 128 chunks = 16 rows x 8 x 16B
            int rr = chk >> 3, cc = chk & 7;
            *(short8*)(h1 + (size_t)(ro + mi * 16 + rr) * DFF_ + co + cc * 8) =
                *(const short8*)(ws_ + rr * 66 + cc * 8);
        }
        asm volatile("s_waitcnt lgkmcnt(0)" ::: "memory");
    }
}

// ---------------- MFMA GEMM 2 (2 blocks/CU): out[sel] = x_sel + h1 @ w2 + b2 ----------------
// 128x128 tile, BK=32, 256 thr (4 waves 2x2, 64x64/wave), double-buffer 32 KiB,
// one barrier + one vmcnt(0) per K-tile; scattered fp32 residual epilogue.
__global__ __launch_bounds__(256, 2) void ffn2_db_kernel(const unsigned short* __restrict__ A,
                                                         const unsigned short* __restrict__ Bt,
                                                         const float* __restrict__ b2,
                                                         const float* __restrict__ x,
                                                         const int* __restrict__ topk,
                                                         float* __restrict__ out) {
    constexpr int K  = DFF_;      // 4096
    constexpr int NT = K / 32;    // 128 K-tiles
    __shared__ __align__(16) unsigned short smem[16384];   // 32 KiB: 2 x (A 4096 | B 4096 shorts)

    const int t    = threadIdx.x;
    const int lane = t & 63;
    const int wid  = t >> 6;
    const int quad = lane >> 4;
    const int lr   = lane & 15;
    const int wr   = wid >> 1;            // 0..1  (M)
    const int wc   = wid & 1;             // 0..1  (N)
    const int row0 = blockIdx.x * 128;
    const int col0 = blockIdx.y * 128;

    // staging: A 512 chunks + B 512 chunks; thread t -> ch t, t+256 in each
    const int ch0 = t, ch1 = t + 256;
    const int rp0 = ch0 >> 3, w0 = (ch0 & 7) ^ (rp0 & 7);
    const int rp1 = ch1 >> 3, w1 = (ch1 & 7) ^ (rp1 & 7);
    const char* aS0 = (const char*)A  + ((size_t)(row0 + rp0 * 2 + (w0 >> 2)) * K + (size_t)(w0 & 3) * 8) * 2;
    const char* aS1 = (const char*)A  + ((size_t)(row0 + rp1 * 2 + (w1 >> 2)) * K + (size_t)(w1 & 3) * 8) * 2;
    const char* bS0 = (const char*)Bt + ((size_t)(col0 + rp0 * 2 + (w0 >> 2)) * K + (size_t)(w0 & 3) * 8) * 2;
    const char* bS1 = (const char*)Bt + ((size_t)(col0 + rp1 * 2 + (w1 >> 2)) * K + (size_t)(w1 & 3) * 8) * 2;
    const int oA0 = ch0 * 8, oA1 = ch1 * 8;
    const int oB0 = 4096 + ch0 * 8, oB1 = 4096 + ch1 * 8;

    const int rbA = wr * 64 + lr, rA2 = rbA >> 1;
    const int aoff = (rA2 * 8 + ((((rbA & 1) << 2) | quad) ^ (rA2 & 7))) * 8;
    const int rbB = wc * 64 + lr, rB2 = rbB >> 1;
    const int boff = 4096 + (rB2 * 8 + ((((rbB & 1) << 2) | quad) ^ (rB2 & 7))) * 8;

    unsigned short* lds0 = smem;
    unsigned short* lds1 = smem + 8192;

    // ---- prologue: stage K-tile 0 ----
    gld16(aS0, lds0 + oA0); gld16(aS1, lds0 + oA1);
    gld16(bS0, lds0 + oB0); gld16(bS1, lds0 + oB1);
    aS0 += 64; aS1 += 64; bS0 += 64; bS1 += 64;
    asm volatile("s_waitcnt vmcnt(0)" ::: "memory");
    __builtin_amdgcn_s_barrier();

    float4v acc[4][4] = {};
    short8 af[4], bq[4];

    auto step = [&](const unsigned short* cur, unsigned short* nxt, bool pf) {
        #pragma unroll
        for (int mi = 0; mi < 4; ++mi) af[mi] = *(const short8*)(cur + aoff + mi * 512);
        #pragma unroll
        for (int ni = 0; ni < 4; ++ni) bq[ni] = *(const short8*)(cur + boff + ni * 512);
        if (pf) {
            gld16(aS0, nxt + oA0); gld16(aS1, nxt + oA1);
            gld16(bS0, nxt + oB0); gld16(bS1, nxt + oB1);
            aS0 += 64; aS1 += 64; bS0 += 64; bS1 += 64;
        }
        __builtin_amdgcn_sched_barrier(0);
        __builtin_amdgcn_s_setprio(1);
        #pragma unroll
        for (int mi = 0; mi < 4; ++mi)
            #pragma unroll
            for (int ni = 0; ni < 4; ++ni)
                acc[mi][ni] = __builtin_amdgcn_mfma_f32_16x16x32_bf16(af[mi], bq[ni], acc[mi][ni], 0, 0, 0);
        __builtin_amdgcn_s_setprio(0);
        asm volatile("s_waitcnt vmcnt(0)" ::: "memory");
        __builtin_amdgcn_s_barrier();
    };

    for (int kt = 0; kt < NT - 2; kt += 2) { step(lds0, lds1, true); step(lds1, lds0, true); }
    step(lds0, lds1, true);    // kt = NT-2
    step(lds1, lds0, false);   // kt = NT-1

    // ---- epilogue: scattered residual stores (identical math/order to r2 ffn2) ----
    #pragma unroll
    for (int mi = 0; mi < 4; ++mi) {
        #pragma unroll
        for (int r = 0; r < 4; ++r) {
            int row = row0 + wr * 64 + mi * 16 + quad * 4 + r;
            int gb = row >> 11;
            int tok = topk[row];
            size_t base = ((size_t)(gb * N_ + tok)) * D_;
            #pragma unroll
            for (int ni = 0; ni < 4; ++ni) {
                int col = col0 + wc * 64 + ni * 16 + lr;
                out[base + col] = x[base + col] + acc[mi][ni][r] + b2[col];
            }
        }
    }
}

extern "C" void kernel_launch(void* const* d_in, const int* in_sizes, int n_in,
                              void* d_out, int out_size, void* d_ws, size_t ws_size,
                              hipStream_t stream) {
    const float* x      = (const float*)d_in[0];
    const float* gate_w = (const float*)d_in[1];
    const float* w1     = (const float*)d_in[2];
    const float* b1     = (const float*)d_in[3];
    const float* w2     = (const float*)d_in[4];
    const float* b2     = (const float*)d_in[5];
    float* out = (float*)d_out;

    char* ws = (char*)d_ws;
    float*          scores = (float*)ws;                                        // 64 KiB
    int*            topk   = (int*)(ws + (64 << 10));                           // 32 KiB
    int*            slot   = (int*)(ws + (96 << 10));                           // 64 KiB
    unsigned short* xsel   = (unsigned short*)(ws + (160 << 10));               // 16 MiB
    unsigned short* w1t    = (unsigned short*)(ws + (160 << 10) + (16 << 20));  // 8 MiB  [4096][1024]
    unsigned short* w2t    = (unsigned short*)(ws + (160 << 10) + (24 << 20));  // 8 MiB  [1024][4096]
    unsigned short* h1     = (unsigned short*)(ws + (160 << 10) + (32 << 20));  // 64 MiB [8192][4096]

    scores_kernel<<<(B_ * N_) / 4, 256, 0, stream>>>(x, gate_w, scores, slot);
    select_topk_kernel<<<B_, 1024, 0, stream>>>(scores, topk, slot);

    transpose_both_kernel<<<8192, 256, 0, stream>>>(w1, w2, w1t, w2t);

    gather_copy_kernel<<<B_ * N_, 256, 0, stream>>>(x, slot, xsel, out);

    ffn1_db_kernel<<<dim3(32, 32), 512, 0, stream>>>(xsel, w1t, b1, h1);
    ffn2_db_kernel<<<dim3(64, 8), 256, 0, stream>>>(h1, w2t, b2, x, topk, out);
}

// Round 4
// 317.885 us; speedup vs baseline: 1.1099x; 1.0374x over previous
//
#include <hip/hip_runtime.h>
#include <math.h>

#define B_   4
#define N_   4096
#define D_   1024
#define DFF_ 4096
#define K_   2048

typedef __attribute__((ext_vector_type(8))) short short8;
typedef __attribute__((ext_vector_type(4))) float float4v;

__device__ __forceinline__ unsigned short f2bf(float f) {
    unsigned int u = __float_as_uint(f);
    u = (u + 0x7fffu + ((u >> 16) & 1u)) >> 16;   // RNE
    return (unsigned short)u;
}

__device__ __forceinline__ void gld16(const void* g, void* l) {
    __builtin_amdgcn_global_load_lds((const __attribute__((address_space(1))) void*)g,
                                     (__attribute__((address_space(3))) void*)l, 16, 0, 0);
}

// ---------------- scores (bit-identical selection math) + slot clear ----------------
__global__ __launch_bounds__(256) void scores_kernel(const float* __restrict__ x,
                                                     const float* __restrict__ gate_w,
                                                     float* __restrict__ scores,
                                                     int* __restrict__ slot) {
    int wave = (blockIdx.x * blockDim.x + threadIdx.x) >> 6;
    int lane = threadIdx.x & 63;
    if (wave >= B_ * N_) return;
    if (lane == 1) slot[wave] = -1;
    const float4* xr = (const float4*)(x + (size_t)wave * D_);
    const float4* g  = (const float4*)gate_w;
    float acc = 0.f;
    #pragma unroll
    for (int j = 0; j < D_ / 4 / 64; ++j) {
        float4 a = xr[lane + j * 64];
        float4 b = g[lane + j * 64];
        acc += a.x * b.x + a.y * b.y + a.z * b.z + a.w * b.w;
    }
    #pragma unroll
    for (int off = 32; off > 0; off >>= 1) acc += __shfl_down(acc, off, 64);
    if (lane == 0) scores[wave] = acc;
}

// ---------------- top-k radix select, wave-level scans; writes topk + global slot map ----------------
__global__ __launch_bounds__(1024) void select_topk_kernel(const float* __restrict__ scores,
                                                           int* __restrict__ topk,
                                                           int* __restrict__ slot) {
    __shared__ unsigned key[N_];
    __shared__ unsigned hist[256];
    __shared__ int sh_bin, sh_rem, sh_ngt;
    __shared__ int wsum[16], woff[16];
    int b = blockIdx.x, tid = threadIdx.x;
    int lane = tid & 63, wid = tid >> 6;

    for (int i = tid; i < N_; i += 1024) {
        unsigned u = __float_as_uint(scores[b * N_ + i]);
        key[i] = (u & 0x80000000u) ? ~u : (u | 0x80000000u);   // monotonic map
    }
    if (tid == 0) sh_ngt = 0;
    __syncthreads();

    unsigned prefix = 0, pmask = 0;
    int rem = K_;
    for (int shift = 24; shift >= 0; shift -= 8) {
        if (tid < 256) hist[tid] = 0;
        __syncthreads();
        for (int i = tid; i < N_; i += 1024) {
            unsigned k = key[i];
            if ((k & pmask) == prefix) atomicAdd(&hist[(k >> shift) & 255u], 1u);
        }
        __syncthreads();
        if (tid < 64) {   // wave 0: suffix scan of 256 bins, 4 bins/lane
            unsigned v0 = hist[4 * lane], v1 = hist[4 * lane + 1];
            unsigned v2 = hist[4 * lane + 2], v3 = hist[4 * lane + 3];
            unsigned s3 = v3, s2 = v2 + s3, s1 = v1 + s2, s0 = v0 + s1;
            unsigned t = s0;
            #pragma unroll
            for (int off = 1; off < 64; off <<= 1) {
                unsigned u = __shfl_down(t, off, 64);
                if (lane + off < 64) t += u;
            }
            unsigned above = t - s0;                  // keys in bins > 4*lane+3
            unsigned S0 = s0 + above, S1 = s1 + above, S2 = s2 + above, S3 = s3 + above;
            unsigned R = (unsigned)rem;
            if (S0 >= R && S1 < R) { sh_bin = 4 * lane;     sh_rem = rem - (int)S1; }
            if (S1 >= R && S2 < R) { sh_bin = 4 * lane + 1; sh_rem = rem - (int)S2; }
            if (S2 >= R && S3 < R) { sh_bin = 4 * lane + 2; sh_rem = rem - (int)S3; }
            if (S3 >= R && above < R) { sh_bin = 4 * lane + 3; sh_rem = rem - (int)above; }
        }
        __syncthreads();
        prefix |= ((unsigned)sh_bin) << shift;
        pmask  |= 0xffu << shift;
        rem = sh_rem;
    }
    unsigned T = prefix;          // exact key of k-th largest
    int c_gt = K_ - rem;          // count strictly greater

    // strictly-greater: ballot-compacted, arbitrary order, slots [0, c_gt)
    for (int i = tid; i < N_; i += 1024) {
        bool p = key[i] > T;
        unsigned long long m = __ballot(p);
        int cnt = __popcll(m);
        int basepos = 0;
        if (lane == 0 && cnt) basepos = atomicAdd(&sh_ngt, cnt);
        basepos = __shfl(basepos, 0, 64);
        if (p) {
            int pos = basepos + __popcll(m & ((1ULL << lane) - 1ULL));
            topk[b * K_ + pos] = i;
            slot[b * N_ + i] = b * K_ + pos;
        }
    }
    // ties: first `rem` by index -> slots [c_gt, K)
    int base = tid * 4, c = 0;
    #pragma unroll
    for (int j = 0; j < 4; ++j) c += (key[base + j] == T);
    int sc = c;
    #pragma unroll
    for (int off = 1; off < 64; off <<= 1) {
        int u = __shfl_up(sc, off, 64);
        if (lane >= off) sc += u;
    }
    if (lane == 63) wsum[wid] = sc;
    __syncthreads();
    if (tid == 0) {
        int run = 0;
        #pragma unroll
        for (int j = 0; j < 16; ++j) { woff[j] = run; run += wsum[j]; }
    }
    __syncthreads();
    int r = woff[wid] + sc - c;   // exclusive prefix among ties
    #pragma unroll
    for (int j = 0; j < 4; ++j) {
        if (key[base + j] == T) {
            if (r < rem) {
                topk[b * K_ + c_gt + r] = base + j;
                slot[b * N_ + base + j] = b * K_ + c_gt + r;
            }
            ++r;
        }
    }
}

// ---------------- fused: selected rows -> bf16 xsel[slot]; unselected -> out copy ----------------
__global__ __launch_bounds__(256) void gather_copy_kernel(const float* __restrict__ x,
                                                          const int* __restrict__ slot,
                                                          unsigned short* __restrict__ xsel,
                                                          float* __restrict__ out) {
    int row = blockIdx.x;
    int t = threadIdx.x;
    int s = slot[row];
    float4 v = ((const float4*)(x + (size_t)row * D_))[t];
    if (s >= 0) {
        ushort4 o;
        o.x = f2bf(v.x); o.y = f2bf(v.y); o.z = f2bf(v.z); o.w = f2bf(v.w);
        ((ushort4*)(xsel + (size_t)s * D_))[t] = o;
    } else {
        ((float4*)(out + (size_t)row * D_))[t] = v;
    }
}

// ---------------- both weight transposes (fp32 [R][C] -> bf16 [C][R]) in one launch ----------------
__global__ __launch_bounds__(256) void transpose_both_kernel(const float* __restrict__ w1,
                                                             const float* __restrict__ w2,
                                                             unsigned short* __restrict__ w1t,
                                                             unsigned short* __restrict__ w2t) {
    __shared__ float tile[32][33];
    int bid = blockIdx.x;
    const float* src; unsigned short* dst; int R, C, bx, by;
    if (bid < 4096) { src = w1; dst = w1t; R = D_;   C = DFF_; bx = bid & 127;          by = bid >> 7; }
    else            { src = w2; dst = w2t; R = DFF_; C = D_;   bx = (bid - 4096) & 31;  by = (bid - 4096) >> 5; }
    int tx = threadIdx.x & 31, ty = threadIdx.x >> 5;   // 32 x 8
    int c = bx * 32 + tx, r0 = by * 32;
    #pragma unroll
    for (int j = ty; j < 32; j += 8) tile[j][tx] = src[(size_t)(r0 + j) * C + c];
    __syncthreads();
    int dc = by * 32 + tx, dr0 = bx * 32;
    #pragma unroll
    for (int j = ty; j < 32; j += 8) dst[(size_t)(dr0 + j) * R + dc] = f2bf(tile[tx][j]);
}

// ======== BK=64 row-sweep XOR swizzle ========
// Row = 64 shorts = 128 B = 8 x 16B chunks = one full bank sweep. Logical chunk (r, c)
// stored at slot r*8 + (c ^ (r&7)); LDS dest linear (global_load_lds), permutation applied
// to global source + ds_read address (same involution). Fragment read (16 lanes, fixed
// chunk, 16 consecutive rows): each 16B slot hit exactly 2x per quarter-wave = free
// (same profile as the r2-verified swizzle; conflicts measured ~0).

// ---------------- MFMA GEMM 1 (BK=64, dbuf, 2 blocks/CU): h1 = gelu(x_sel @ w1 + b1) ----------------
// 128x128 tile, 256 thr (4 waves 2Mx2N, 64x64/wave), 16 K-phases of 32 MFMA/wave,
// one vmcnt(0)+barrier per phase. Epilogue: full-128B-line h1 stores.
__global__ __launch_bounds__(256, 2) void ffn1_k64_kernel(const unsigned short* __restrict__ A,
                                                          const unsigned short* __restrict__ Bt,
                                                          const float* __restrict__ b1,
                                                          unsigned short* __restrict__ h1) {
    constexpr int K  = D_;        // 1024
    constexpr int NT = K / 64;    // 16 K-tiles
    __shared__ __align__(16) unsigned short smem[32768];   // 64 KiB: 2 x (A 8192 | B 8192 shorts)

    const int t    = threadIdx.x;
    const int lane = t & 63;
    const int wid  = t >> 6;
    const int quad = lane >> 4;
    const int lr   = lane & 15;
    const int wr   = wid >> 1;            // 0..1  (M)
    const int wc   = wid & 1;             // 0..1  (N)
    const int row0 = blockIdx.x * 128;
    const int col0 = blockIdx.y * 128;

    // staging: A region = 1024 chunks (128 rows x 8), B same; thread t -> slots t+j*256.
    const char* aS[4]; const char* bS[4]; int oA[4], oB[4];
    #pragma unroll
    for (int j = 0; j < 4; ++j) {
        int s = t + j * 256;
        int r = s >> 3, c = (s & 7) ^ (r & 7);
        aS[j] = (const char*)A  + ((size_t)(row0 + r) * K + (size_t)c * 8) * 2;
        bS[j] = (const char*)Bt + ((size_t)(col0 + r) * K + (size_t)c * 8) * 2;
        oA[j] = s * 8;
        oB[j] = 8192 + s * 8;
    }

    // fragment bases (swizzled); mi/ni advance 16 rows = +128 slots = +1024 shorts
    const int rbA = wr * 64 + lr;
    const int aoff0 = (rbA * 8 + (quad       ^ (rbA & 7))) * 8;
    const int aoff1 = (rbA * 8 + ((4 + quad) ^ (rbA & 7))) * 8;
    const int rbB = wc * 64 + lr;
    const int boff0 = 8192 + (rbB * 8 + (quad       ^ (rbB & 7))) * 8;
    const int boff1 = 8192 + (rbB * 8 + ((4 + quad) ^ (rbB & 7))) * 8;

    unsigned short* lds0 = smem;
    unsigned short* lds1 = smem + 16384;

    // ---- prologue: stage K-tile 0 ----
    #pragma unroll
    for (int j = 0; j < 4; ++j) { gld16(aS[j], lds0 + oA[j]); gld16(bS[j], lds0 + oB[j]); }
    #pragma unroll
    for (int j = 0; j < 4; ++j) { aS[j] += 128; bS[j] += 128; }
    asm volatile("s_waitcnt vmcnt(0)" ::: "memory");
    __builtin_amdgcn_s_barrier();

    float4v acc[4][4] = {};

    auto step = [&](const unsigned short* cur, unsigned short* nxt, bool pf) {
        short8 af[4], bq[4];
        // ---- k-half 0 frags; stage next tile early ----
        #pragma unroll
        for (int mi = 0; mi < 4; ++mi) af[mi] = *(const short8*)(cur + aoff0 + mi * 1024);
        #pragma unroll
        for (int ni = 0; ni < 4; ++ni) bq[ni] = *(const short8*)(cur + boff0 + ni * 1024);
        if (pf) {
            #pragma unroll
            for (int j = 0; j < 4; ++j) { gld16(aS[j], nxt + oA[j]); gld16(bS[j], nxt + oB[j]); }
            #pragma unroll
            for (int j = 0; j < 4; ++j) { aS[j] += 128; bS[j] += 128; }
        }
        __builtin_amdgcn_sched_barrier(0);
        __builtin_amdgcn_s_setprio(1);
        #pragma unroll
        for (int mi = 0; mi < 4; ++mi)
            #pragma unroll
            for (int ni = 0; ni < 4; ++ni)
                acc[mi][ni] = __builtin_amdgcn_mfma_f32_16x16x32_bf16(af[mi], bq[ni], acc[mi][ni], 0, 0, 0);
        __builtin_amdgcn_s_setprio(0);
        // ---- k-half 1 ----
        #pragma unroll
        for (int mi = 0; mi < 4; ++mi) af[mi] = *(const short8*)(cur + aoff1 + mi * 1024);
        #pragma unroll
        for (int ni = 0; ni < 4; ++ni) bq[ni] = *(const short8*)(cur + boff1 + ni * 1024);
        __builtin_amdgcn_s_setprio(1);
        #pragma unroll
        for (int mi = 0; mi < 4; ++mi)
            #pragma unroll
            for (int ni = 0; ni < 4; ++ni)
                acc[mi][ni] = __builtin_amdgcn_mfma_f32_16x16x32_bf16(af[mi], bq[ni], acc[mi][ni], 0, 0, 0);
        __builtin_amdgcn_s_setprio(0);
        asm volatile("s_waitcnt vmcnt(0)" ::: "memory");   // next tile landed (hidden under MFMA)
        __builtin_amdgcn_s_barrier();
    };

    for (int kt = 0; kt < NT - 2; kt += 2) { step(lds0, lds1, true); step(lds1, lds0, true); }
    step(lds0, lds1, true);    // kt = NT-2
    step(lds1, lds0, false);   // kt = NT-1 (trailing barrier guards smem reuse)

    // ---- epilogue: bias+GELU -> bf16 via per-wave LDS (16 rows x 66 shorts), full-line stores ----
    float bias[4];
    #pragma unroll
    for (int ni = 0; ni < 4; ++ni) bias[ni] = b1[col0 + wc * 64 + ni * 16 + lr];
    unsigned short* ws_ = smem + wid * 1056;   // 4 waves x 1056 shorts
    const int ro = row0 + wr * 64, co = col0 + wc * 64;
    #pragma unroll
    for (int mi = 0; mi < 4; ++mi) {
        #pragma unroll
        for (int ni = 0; ni < 4; ++ni)
            #pragma unroll
            for (int r = 0; r < 4; ++r) {
                float u = acc[mi][ni][r] + bias[ni];
                float tt = 1.5957691216057308f * u * (1.0f + 0.044715f * u * u);
                float g = u / (1.0f + __expf(-tt));
                ws_[(quad * 4 + r) * 66 + ni * 16 + lr] = f2bf(g);
            }
        asm volatile("s_waitcnt lgkmcnt(0)" ::: "memory");
        #pragma unroll
        for (int j = 0; j < 2; ++j) {
            int chk = lane + j * 64;          // 128 chunks = 16 rows x 8 x 16B
            int rr = chk >> 3, cc = chk & 7;
            *(short8*)(h1 + (size_t)(ro + mi * 16 + rr) * DFF_ + co + cc * 8) =
                *(const short8*)(ws_ + rr * 66 + cc * 8);
        }
        asm volatile("s_waitcnt lgkmcnt(0)" ::: "memory");
    }
}

// ---------------- MFMA GEMM 2 (BK=64, dbuf, 2 blocks/CU): out[sel] = x_sel + h1 @ w2 + b2 ----------------
// 128x128 tile, 256 thr (4 waves 2x2, 64x64/wave), 64 K-phases of 32 MFMA/wave,
// one vmcnt(0)+barrier per phase; scattered fp32 residual epilogue.
__global__ __launch_bounds__(256, 2) void ffn2_k64_kernel(const unsigned short* __restrict__ A,
                                                          const unsigned short* __restrict__ Bt,
                                                          const float* __restrict__ b2,
                                                          const float* __restrict__ x,
                                                          const int* __restrict__ topk,
                                                          float* __restrict__ out) {
    constexpr int K  = DFF_;      // 4096
    constexpr int NT = K / 64;    // 64 K-tiles
    __shared__ __align__(16) unsigned short smem[32768];   // 64 KiB: 2 x (A 8192 | B 8192 shorts)

    const int t    = threadIdx.x;
    const int lane = t & 63;
    const int wid  = t >> 6;
    const int quad = lane >> 4;
    const int lr   = lane & 15;
    const int wr   = wid >> 1;            // 0..1  (M)
    const int wc   = wid & 1;             // 0..1  (N)
    const int row0 = blockIdx.x * 128;
    const int col0 = blockIdx.y * 128;

    const char* aS[4]; const char* bS[4]; int oA[4], oB[4];
    #pragma unroll
    for (int j = 0; j < 4; ++j) {
        int s = t + j * 256;
        int r = s >> 3, c = (s & 7) ^ (r & 7);
        aS[j] = (const char*)A  + ((size_t)(row0 + r) * K + (size_t)c * 8) * 2;
        bS[j] = (const char*)Bt + ((size_t)(col0 + r) * K + (size_t)c * 8) * 2;
        oA[j] = s * 8;
        oB[j] = 8192 + s * 8;
    }

    const int rbA = wr * 64 + lr;
    const int aoff0 = (rbA * 8 + (quad       ^ (rbA & 7))) * 8;
    const int aoff1 = (rbA * 8 + ((4 + quad) ^ (rbA & 7))) * 8;
    const int rbB = wc * 64 + lr;
    const int boff0 = 8192 + (rbB * 8 + (quad       ^ (rbB & 7))) * 8;
    const int boff1 = 8192 + (rbB * 8 + ((4 + quad) ^ (rbB & 7))) * 8;

    unsigned short* lds0 = smem;
    unsigned short* lds1 = smem + 16384;

    // ---- prologue: stage K-tile 0 ----
    #pragma unroll
    for (int j = 0; j < 4; ++j) { gld16(aS[j], lds0 + oA[j]); gld16(bS[j], lds0 + oB[j]); }
    #pragma unroll
    for (int j = 0; j < 4; ++j) { aS[j] += 128; bS[j] += 128; }
    asm volatile("s_waitcnt vmcnt(0)" ::: "memory");
    __builtin_amdgcn_s_barrier();

    float4v acc[4][4] = {};

    auto step = [&](const unsigned short* cur, unsigned short* nxt, bool pf) {
        short8 af[4], bq[4];
        #pragma unroll
        for (int mi = 0; mi < 4; ++mi) af[mi] = *(const short8*)(cur + aoff0 + mi * 1024);
        #pragma unroll
        for (int ni = 0; ni < 4; ++ni) bq[ni] = *(const short8*)(cur + boff0 + ni * 1024);
        if (pf) {
            #pragma unroll
            for (int j = 0; j < 4; ++j) { gld16(aS[j], nxt + oA[j]); gld16(bS[j], nxt + oB[j]); }
            #pragma unroll
            for (int j = 0; j < 4; ++j) { aS[j] += 128; bS[j] += 128; }
        }
        __builtin_amdgcn_sched_barrier(0);
        __builtin_amdgcn_s_setprio(1);
        #pragma unroll
        for (int mi = 0; mi < 4; ++mi)
            #pragma unroll
            for (int ni = 0; ni < 4; ++ni)
                acc[mi][ni] = __builtin_amdgcn_mfma_f32_16x16x32_bf16(af[mi], bq[ni], acc[mi][ni], 0, 0, 0);
        __builtin_amdgcn_s_setprio(0);
        #pragma unroll
        for (int mi = 0; mi < 4; ++mi) af[mi] = *(const short8*)(cur + aoff1 + mi * 1024);
        #pragma unroll
        for (int ni = 0; ni < 4; ++ni) bq[ni] = *(const short8*)(cur + boff1 + ni * 1024);
        __builtin_amdgcn_s_setprio(1);
        #pragma unroll
        for (int mi = 0; mi < 4; ++mi)
            #pragma unroll
            for (int ni = 0; ni < 4; ++ni)
                acc[mi][ni] = __builtin_amdgcn_mfma_f32_16x16x32_bf16(af[mi], bq[ni], acc[mi][ni], 0, 0, 0);
        __builtin_amdgcn_s_setprio(0);
        asm volatile("s_waitcnt vmcnt(0)" ::: "memory");
        __builtin_amdgcn_s_barrier();
    };

    for (int kt = 0; kt < NT - 2; kt += 2) { step(lds0, lds1, true); step(lds1, lds0, true); }
    step(lds0, lds1, true);    // kt = NT-2
    step(lds1, lds0, false);   // kt = NT-1

    // ---- epilogue: scattered residual stores (identical math/order to r3 ffn2) ----
    #pragma unroll
    for (int mi = 0; mi < 4; ++mi) {
        #pragma unroll
        for (int r = 0; r < 4; ++r) {
            int row = row0 + wr * 64 + mi * 16 + quad * 4 + r;
            int gb = row >> 11;
            int tok = topk[row];
            size_t base = ((size_t)(gb * N_ + tok)) * D_;
            #pragma unroll
            for (int ni = 0; ni < 4; ++ni) {
                int col = col0 + wc * 64 + ni * 16 + lr;
                out[base + col] = x[base + col] + acc[mi][ni][r] + b2[col];
            }
        }
    }
}

extern "C" void kernel_launch(void* const* d_in, const int* in_sizes, int n_in,
                              void* d_out, int out_size, void* d_ws, size_t ws_size,
                              hipStream_t stream) {
    const float* x      = (const float*)d_in[0];
    const float* gate_w = (const float*)d_in[1];
    const float* w1     = (const float*)d_in[2];
    const float* b1     = (const float*)d_in[3];
    const float* w2     = (const float*)d_in[4];
    const float* b2     = (const float*)d_in[5];
    float* out = (float*)d_out;

    char* ws = (char*)d_ws;
    float*          scores = (float*)ws;                                        // 64 KiB
    int*            topk   = (int*)(ws + (64 << 10));                           // 32 KiB
    int*            slot   = (int*)(ws + (96 << 10));                           // 64 KiB
    unsigned short* xsel   = (unsigned short*)(ws + (160 << 10));               // 16 MiB
    unsigned short* w1t    = (unsigned short*)(ws + (160 << 10) + (16 << 20));  // 8 MiB  [4096][1024]
    unsigned short* w2t    = (unsigned short*)(ws + (160 << 10) + (24 << 20));  // 8 MiB  [1024][4096]
    unsigned short* h1     = (unsigned short*)(ws + (160 << 10) + (32 << 20));  // 64 MiB [8192][4096]

    scores_kernel<<<(B_ * N_) / 4, 256, 0, stream>>>(x, gate_w, scores, slot);
    select_topk_kernel<<<B_, 1024, 0, stream>>>(scores, topk, slot);

    transpose_both_kernel<<<8192, 256, 0, stream>>>(w1, w2, w1t, w2t);

    gather_copy_kernel<<<B_ * N_, 256, 0, stream>>>(x, slot, xsel, out);

    ffn1_k64_kernel<<<dim3(64, 32), 256, 0, stream>>>(xsel, w1t, b1, h1);
    ffn2_k64_kernel<<<dim3(64, 8), 256, 0, stream>>>(h1, w2t, b2, x, topk, out);
}